// Round 11
// baseline (329.047 us; speedup 1.0000x reference)
//
#include <hip/hip_runtime.h>

// ---------------------------------------------------------------------------
// HeteroGNN fused pipeline for MI355X (gfx950).
//   loc_h = relu(loc_x @ W_loc + b_loc)          [100000, 64]
//   evt_h = relu(evt_x @ W_evt + b_evt)          [200000, 64]
//   agg   = segment_mean(evt_h[src] -> dst)      (fused into head, R16)
//   h2    = relu(agg @ W_l + b_l + loc_h @ W_r)  (MFMA)
//   h1    = relu(h2 @ W_h1 + b_h1)               (MFMA)
//   out   = h1 @ W_h2 + b_h2                     [100000]
// Proj verdict (R6-R15): pinned 66-72us across SIX structures when clean
//   (one-shot, persistent+L2-B, +LDS-B, coalesced-restage, depth-2 reg
//   pipeline, 3x grid). 2.9TB/s demand-side. bounds(256,4)=>64-VGPR spill
//   (NEVER). Contiguous ranges lose L3 (keep strided). Occupancy pinned
//   ~26% regardless of grid. Proj is DONE at bounds(256,3)+strided+LDS-B.
// R16: aggregate fused into head (agg_head_kernel): each wave gathers its
//   16 rows (exact R13 per-row reduction, same order -> same absmax) into
//   wave-private LDS [16][72] (2-way-free banks, no barrier), then runs
//   the head MFMA reading A-frags from LDS. Kills 25.6MB agg round-trip +
//   one launch. 5 launches total.
// R17: identical to R16 (R16 bench was a GPUAcquisitionTimeout, never ran).
// ---------------------------------------------------------------------------

#define N_LOC 100000
#define N_EVT 200000
#define E_CNT 1000000
#define NTILES 6250   // N_LOC / 16
#define NBKT   256
#define BKT_L  391    // locations per bucket (255*391=99705 <= 99999)
#define CAPG   6000   // per-bucket capacity (avg 3906, sigma 62 -> +33 sigma)
#define QCAP   32     // passA LDS queue depth per bucket
#define BKT_BLK 512   // passA blocks (2 per CU at 64KB LDS)
#define PERB   1954   // edges per passA block (512*1954 >= 1e6)

#define PROJ_EVT_BLK 1536
#define PROJ_LOC_BLK 768
#define PROJ_BLK_TOT (PROJ_EVT_BLK + PROJ_LOC_BLK)
#define EVT_TILES 12500   // 200000/16
#define LOC_TILES 6250    // 100000/16
#define AGGH_BLK  1563    // ceil(6250/4) tiles, 1 tile per wave

typedef __attribute__((ext_vector_type(8))) short short8;   // 8 x bf16
typedef __attribute__((ext_vector_type(4))) float floatx4;  // MFMA C/D frag
typedef __attribute__((ext_vector_type(8))) unsigned short ushort8v;

__device__ __forceinline__ float b2f(unsigned short u) {
    unsigned int x = ((unsigned int)u) << 16;
    return __builtin_bit_cast(float, x);
}
__device__ __forceinline__ unsigned short f2b(float f) {
    unsigned int x = __builtin_bit_cast(unsigned int, f);
    unsigned int r = (x + 0x7fffu + ((x >> 16) & 1u)) >> 16;  // RNE
    return (unsigned short)r;
}
__device__ __forceinline__ float loadf(const void* p, int f32, size_t i) {
    return f32 ? ((const float*)p)[i] : b2f(((const unsigned short*)p)[i]);
}

// ---------------------------------------------------------------------------
// KA: detect + zero + permute, one launch, 28 blocks.
// wp_all offsets (elements): evt 0, loc 8192, W_l 16384, W_r 20480, W_h1 24576
// ---------------------------------------------------------------------------
__global__ __launch_bounds__(256) void prep_kernel(
    const void* t0, const void* t1, const int* eidx,
    const void* t3, const void* t4, const void* t5, const void* t6,
    const void* t7, const void* t8, const void* t9, const void* t10,
    const void* t11, const void* t12, const void* t13,
    int* flags, int* gbc, unsigned short* __restrict__ wp_all) {
    int b = blockIdx.x, tid = threadIdx.x;
    __shared__ int s0, s1;

    if (b == 14) { gbc[tid] = 0; return; }

    if (b >= 15) {                           // permute, self-detecting
        int pb = b - 15;
        const void* W; int K, N, bstart, off;
        if (pb < 4)       { W = t5;  K = 128; N = 64; bstart = 0;  off = 0; }
        else if (pb < 8)  { W = t3;  K = 128; N = 64; bstart = 4;  off = 8192; }
        else if (pb < 10) { W = t7;  K = 64;  N = 64; bstart = 8;  off = 16384; }
        else if (pb < 12) { W = t9;  K = 64;  N = 64; bstart = 10; off = 20480; }
        else              { W = t10; K = 64;  N = 32; bstart = 12; off = 24576; }
        if (tid == 0) s0 = 0;
        __syncthreads();
        int nsamp = 2 * K * N; if (nsamp > 1024) nsamp = 1024;
        const unsigned short* h = (const unsigned short*)W;
        int susp = 0;
        for (int i = tid; i < nsamp; i += 256)
            if (((h[i] >> 7) & 0xFF) >= 0x90) susp++;
        if (susp) atomicAdd(&s0, susp);
        __syncthreads();
        int f32 = (s0 * 16 >= nsamp) ? 1 : 0;

        int idx  = (pb - bstart) * 256 + tid;
        int nk   = K >> 5;
        int f    = idx >> 6;
        int lane = idx & 63;
        int t  = f / nk;
        int kk = f - t * nk;
        int n  = t * 16 + (lane & 15);
        int k0 = kk * 32 + (lane >> 4) * 8;
        unsigned short tmp[8];
#pragma unroll
        for (int j = 0; j < 8; ++j) {
            size_t src = (size_t)(k0 + j) * N + n;
            tmp[j] = f32 ? f2b(((const float*)W)[src])
                         : ((const unsigned short*)W)[src];
        }
#pragma unroll
        for (int j = 0; j < 8; ++j) wp_all[(size_t)off + (size_t)idx * 8 + j] = tmp[j];
        return;
    }

    if (tid == 0) { s0 = 0; s1 = 0; }
    __syncthreads();
    if (b == 13) {   // edge_index: int64 => all odd 32-bit words zero
        if (tid < 128) {
            if (eidx[2 * tid] != 0) atomicAdd(&s0, 1);
            if (eidx[2 * tid + 1] != 0) atomicAdd(&s1, 1);
        }
        __syncthreads();
        if (tid == 0) flags[2] = (s1 == 0 && s0 > 32) ? 1 : 0;
        return;
    }
    const void* ptrs[13] = {t0, t1, t3, t4, t5, t6, t7, t8, t9, t10, t11, t12, t13};
    const int   cnts[13] = {12800000, 25600000, 8192, 64, 8192, 64,
                            4096, 64, 4096, 2048, 32, 32, 1};
    const int   slot[13] = {0, 1, 3, 4, 5, 6, 7, 8, 9, 10, 11, 12, 13};
    int nsamp = 2 * cnts[b];
    if (nsamp > 1024) nsamp = 1024;
    const unsigned short* h = (const unsigned short*)ptrs[b];
    int susp = 0;
    for (int i = tid; i < nsamp; i += 256)
        if (((h[i] >> 7) & 0xFF) >= 0x90) susp++;
    if (susp) atomicAdd(&s0, susp);
    __syncthreads();
    if (tid == 0) flags[slot[b]] = (s0 * 16 >= nsamp) ? 1 : 0;
}

// ---------------------------------------------------------------------------
// K1: both projections. R10 inner loop (strided tiles, 1-deep prefetch,
// split fx paths, LDS-B), bounds(256,3), grid 1536+768. PROVEN CONFIG.
// ---------------------------------------------------------------------------
__global__ __launch_bounds__(256, 3) void proj_both_kernel(
    const void* __restrict__ evt_x, const void* __restrict__ loc_x,
    const unsigned short* __restrict__ wp_all,
    const void* __restrict__ b_evt, const void* __restrict__ b_loc,
    unsigned short* __restrict__ evt_h, unsigned short* __restrict__ loc_h,
    const int* __restrict__ flags) {
    __shared__ unsigned short bs[8192];   // 16 KB: B in MFMA frag order
    int blk = blockIdx.x;
    int tid = threadIdx.x, lane = tid & 63, wv = tid >> 6;
    int l15 = lane & 15, quad = lane >> 4;

    const void* X; const unsigned short* Wp; const void* bias;
    unsigned short* Y; int fx, fb, w0, nw, ntile;
    if (blk < PROJ_EVT_BLK) {
        X = evt_x; Wp = wp_all;        bias = b_evt; Y = evt_h;
        fx = flags[1]; fb = flags[6];
        w0 = blk * 4 + wv; nw = PROJ_EVT_BLK * 4; ntile = EVT_TILES;
    } else {
        X = loc_x; Wp = wp_all + 8192; bias = b_loc; Y = loc_h;
        fx = flags[0]; fb = flags[4];
        w0 = (blk - PROJ_EVT_BLK) * 4 + wv; nw = PROJ_LOC_BLK * 4; ntile = LOC_TILES;
    }

    // cooperative B stage: 1024 x short8, coalesced
    {
        const short8* src = reinterpret_cast<const short8*>(Wp);
        short8* dst = reinterpret_cast<short8*>(bs);
#pragma unroll
        for (int i = 0; i < 4; ++i) dst[tid + i * 256] = src[tid + i * 256];
    }
    __syncthreads();

    float bv[4];
#pragma unroll
    for (int q = 0; q < 4; ++q) bv[q] = loadf(bias, fb, q * 16 + l15);

    if (w0 >= ntile) return;

    // shared epilogue: LDS-B MFMA + bias/relu/store
    auto mfma_store = [&](const short8* a, int t) {
        floatx4 acc[4];
#pragma unroll
        for (int q = 0; q < 4; ++q) acc[q] = (floatx4)0.0f;
#pragma unroll
        for (int q = 0; q < 4; ++q) {
            short8 bq[4];
#pragma unroll
            for (int kk = 0; kk < 4; ++kk)
                bq[kk] = *reinterpret_cast<const short8*>(
                    &bs[((q * 4 + kk) * 64 + lane) * 8]);
#pragma unroll
            for (int kk = 0; kk < 4; ++kk)
                acc[q] = __builtin_amdgcn_mfma_f32_16x16x32_bf16(
                    a[kk], bq[kk], acc[q], 0, 0, 0);
        }
#pragma unroll
        for (int q = 0; q < 4; ++q)
#pragma unroll
            for (int r = 0; r < 4; ++r) {
                float v = acc[q][r] + bv[q];
                v = v > 0.0f ? v : 0.0f;
                Y[(size_t)(t * 16 + quad * 4 + r) * 64 + q * 16 + l15] = f2b(v);
            }
    };

    if (fx) {
        // --- fp32 input path: only pf[8] staging live (32 VGPRs) ---
        const float* Xf = (const float*)X;
        float4 pf[8];
        auto issueF = [&](int t) {
            const float* xr = Xf + (size_t)(t * 16 + l15) * 128 + quad * 8;
#pragma unroll
            for (int kk = 0; kk < 4; ++kk) {
                pf[kk * 2]     = *reinterpret_cast<const float4*>(xr + kk * 32);
                pf[kk * 2 + 1] = *reinterpret_cast<const float4*>(xr + kk * 32 + 4);
            }
        };
        issueF(w0);
        for (int t = w0; t < ntile; t += nw) {
            short8 a[4];
#pragma unroll
            for (int kk = 0; kk < 4; ++kk) {
                float4 p0 = pf[kk * 2], p1 = pf[kk * 2 + 1];
                short8 v;
                v[0] = (short)f2b(p0.x); v[1] = (short)f2b(p0.y);
                v[2] = (short)f2b(p0.z); v[3] = (short)f2b(p0.w);
                v[4] = (short)f2b(p1.x); v[5] = (short)f2b(p1.y);
                v[6] = (short)f2b(p1.z); v[7] = (short)f2b(p1.w);
                a[kk] = v;
            }
            int tn = t + nw;
            if (tn < ntile) issueF(tn);   // next tile in flight during MFMA+store
            mfma_store(a, t);
        }
    } else {
        // --- bf16 input path: only an[4] staging live (16 VGPRs) ---
        const unsigned short* Xh = (const unsigned short*)X;
        short8 an[4];
        auto issueH = [&](int t) {
            const unsigned short* xr = Xh + (size_t)(t * 16 + l15) * 128 + quad * 8;
#pragma unroll
            for (int kk = 0; kk < 4; ++kk)
                an[kk] = *reinterpret_cast<const short8*>(xr + kk * 32);
        };
        issueH(w0);
        for (int t = w0; t < ntile; t += nw) {
            short8 a[4];
#pragma unroll
            for (int kk = 0; kk < 4; ++kk) a[kk] = an[kk];
            int tn = t + nw;
            if (tn < ntile) issueH(tn);
            mfma_store(a, t);
        }
    }
}

// ---------------------------------------------------------------------------
// K2a (passA): bucket edges by dst/391 via LDS queues; flush 128B bursts.
// ---------------------------------------------------------------------------
__global__ __launch_bounds__(256) void bucket_kernel(
    const int* __restrict__ eidx, uint2* __restrict__ bkt,
    int* __restrict__ gbc, const int* __restrict__ flags) {
    __shared__ uint2 queue[NBKT][QCAP];   // 64 KB
    __shared__ int qcnt[NBKT];
    int tid = threadIdx.x, blk = blockIdx.x;
    qcnt[tid] = 0;
    __syncthreads();
    int f64 = flags[2];
    const long long* e64 = (const long long*)eidx;
    int e0 = blk * PERB;
    int e1 = e0 + PERB; if (e1 > E_CNT) e1 = E_CNT;
    const int rounds = (PERB + 255) / 256;

    for (int r = 0; r < rounds; ++r) {
        int e = e0 + r * 256 + tid;
        if (e < e1) {
            int src, dst;
            if (f64) { src = (int)e64[e]; dst = (int)e64[E_CNT + e]; }
            else     { src = eidx[e];     dst = eidx[E_CNT + e]; }
            if ((unsigned)dst < (unsigned)N_LOC && (unsigned)src < (unsigned)N_EVT) {
                int bk = dst / BKT_L;
                int pos = atomicAdd(&qcnt[bk], 1);
                if (pos < QCAP) {
                    queue[bk][pos] = make_uint2((unsigned)src, (unsigned)dst);
                } else {   // overflow (astronomically rare): direct store
                    int p = atomicAdd(&gbc[bk], 1);
                    if (p < CAPG) bkt[(size_t)bk * CAPG + p] = make_uint2(src, dst);
                }
            }
        }
        __syncthreads();
        // flush phase: thread t owns bucket t
        int n = qcnt[tid]; if (n > QCAP) n = QCAP;
        while (n >= 16) {
            int gp = atomicAdd(&gbc[tid], 16);
            if (gp + 16 <= CAPG) {
                uint2* d = bkt + (size_t)tid * CAPG + gp;
#pragma unroll
                for (int j = 0; j < 16; ++j) d[j] = queue[tid][j];
            }
#pragma unroll
            for (int j = 16; j < QCAP; ++j) queue[tid][j - 16] = queue[tid][j];
            n -= 16;
        }
        qcnt[tid] = n;
        __syncthreads();
    }
    // tail flush
    int n = qcnt[tid]; if (n > QCAP) n = QCAP;
    if (n > 0) {
        int gp = atomicAdd(&gbc[tid], n);
        for (int j = 0; j < n; ++j)
            if (gp + j < CAPG) bkt[(size_t)tid * CAPG + gp + j] = queue[tid][j];
    }
}

// ---------------------------------------------------------------------------
// K2c: per-bucket local CSR build; gbc scan fused (each block re-scans 256
// counts in LDS). All global writes coalesced.
// ---------------------------------------------------------------------------
__global__ __launch_bounds__(256) void csr_build_kernel(
    const uint2* __restrict__ bkt, const int* __restrict__ gbc,
    int* __restrict__ rowptr, int* __restrict__ csr) {
    __shared__ int sg[256];
    __shared__ int lcnt[512];
    __shared__ int lscan[512];
    __shared__ int lcsr[CAPG];
    int b = blockIdx.x, tid = threadIdx.x;
    int loc0 = b * BKT_L;
    int nloc = N_LOC - loc0; if (nloc > BKT_L) nloc = BKT_L;

    // fused exclusive scan of clamped gbc
    int gv = gbc[tid]; if (gv > CAPG) gv = CAPG;
    sg[tid] = gv;
    __syncthreads();
    for (int d = 1; d < 256; d <<= 1) {
        int x = (tid >= d) ? sg[tid - d] : 0;
        __syncthreads();
        sg[tid] += x;
        __syncthreads();
    }
    int cntE = gbc[b]; if (cntE > CAPG) cntE = CAPG;
    int base = sg[b] - cntE;          // exclusive prefix
    const uint2* bp = bkt + (size_t)b * CAPG;

    int i0 = tid, i1 = tid + 256;
    lcnt[i0] = 0; lcnt[i1] = 0;
    __syncthreads();
    // count
    for (int i = tid; i < cntE; i += 256) {
        int d = (int)bp[i].y - loc0;
        atomicAdd(&lcnt[d], 1);
    }
    __syncthreads();
    // inclusive scan over 512 (Hillis-Steele, 2 elems/thread)
    lscan[i0] = lcnt[i0]; lscan[i1] = lcnt[i1];
    __syncthreads();
    for (int d = 1; d < 512; d <<= 1) {
        int v0 = (i0 >= d) ? lscan[i0 - d] : 0;
        int v1 = (i1 >= d) ? lscan[i1 - d] : 0;
        __syncthreads();
        lscan[i0] += v0; lscan[i1] += v1;
        __syncthreads();
    }
    // rowptr (exclusive) + reset lcnt to cursor start
    for (int i = tid; i < nloc; i += 256) {
        int excl = lscan[i] - lcnt[i];
        rowptr[loc0 + i] = base + excl;
        lcnt[i] = excl;
    }
    if (b == NBKT - 1 && tid == 0) rowptr[N_LOC] = base + cntE;
    __syncthreads();
    // scatter into LDS csr segment
    for (int i = tid; i < cntE; i += 256) {
        uint2 pr = bp[i];
        int d = (int)pr.y - loc0;
        int p = atomicAdd(&lcnt[d], 1);
        if (p < CAPG) lcsr[p] = (int)pr.x;
    }
    __syncthreads();
    // contiguous flush
    for (int i = tid; i < cntE; i += 256) csr[base + i] = lcsr[i];
}

// ---------------------------------------------------------------------------
// K3+K4 fused (R16): agg_head. One wave = one 16-row tile. Wave gathers its
// 16 rows (exact R13 reduction: eo=lane>>3 edge slot, cg=lane&7 col group,
// shfl_xor 8/16/32) into wave-private LDS [16][72] (pitch 72 shorts: rows
// spread 2-way across banks, 16B-aligned), then runs the head MFMA with
// A-frags from LDS. loc_h frags issued before the gather to overlap.
// LDS: 20KB B + 8KB h2s + 9KB ag = 37.2KB -> 4 blocks/CU possible.
// ---------------------------------------------------------------------------
__global__ __launch_bounds__(256, 3) void agg_head_kernel(
    const unsigned short* __restrict__ evt_h,
    const unsigned short* __restrict__ loc_h,
    const int* __restrict__ rowptr, const int* __restrict__ csr,
    const unsigned short* __restrict__ wp_all,
    const void* __restrict__ bl, const void* __restrict__ bh1,
    const void* __restrict__ wh2, const void* __restrict__ bh2,
    void* __restrict__ out, const int* __restrict__ flags) {
    __shared__ unsigned short bls[4096];     // W_l frags, 8 KB
    __shared__ unsigned short brs[4096];     // W_r frags, 8 KB
    __shared__ unsigned short b1s[2048];     // W_h1 frags, 4 KB
    __shared__ unsigned short h2s[4][16 * 64];   // 8 KB
    __shared__ unsigned short ag[4][16 * 72];    // 9 KB, pitch 72
    int tid = threadIdx.x, lane = tid & 63, wv = tid >> 6;
    int l15 = lane & 15, quad = lane >> 4;
    int fbl = flags[8], fbh1 = flags[11], fwh2 = flags[12], fbh2 = flags[13];
    int fout = flags[0];
    const unsigned short* wp_l  = wp_all + 16384;
    const unsigned short* wp_r  = wp_all + 20480;
    const unsigned short* wp_h1 = wp_all + 24576;

    {   // cooperative stage: coalesced short8 copies
        const short8* sl = reinterpret_cast<const short8*>(wp_l);
        const short8* sr = reinterpret_cast<const short8*>(wp_r);
        const short8* s1 = reinterpret_cast<const short8*>(wp_h1);
        short8* dl = reinterpret_cast<short8*>(bls);
        short8* dr = reinterpret_cast<short8*>(brs);
        short8* d1 = reinterpret_cast<short8*>(b1s);
        dl[tid] = sl[tid]; dl[tid + 256] = sl[tid + 256];
        dr[tid] = sr[tid]; dr[tid + 256] = sr[tid + 256];
        d1[tid] = s1[tid];
    }
    __syncthreads();

    float bbl[4], bh1v[2], w2v[2];
#pragma unroll
    for (int q = 0; q < 4; ++q) bbl[q] = loadf(bl, fbl, q * 16 + l15);
#pragma unroll
    for (int q = 0; q < 2; ++q) {
        bh1v[q] = loadf(bh1, fbh1, q * 16 + l15);
        w2v[q]  = loadf(wh2, fwh2, q * 16 + l15);
    }
    float bb2 = loadf(bh2, fbh2, 0);

    int tile = blockIdx.x * 4 + wv;
    if (tile >= NTILES) return;

    // issue loc_h fragments now; they fly under the gather loop
    short8 cl[2];
#pragma unroll
    for (int kk = 0; kk < 2; ++kk)
        cl[kk] = *reinterpret_cast<const short8*>(
            loc_h + (size_t)(tile * 16 + l15) * 64 + kk * 32 + quad * 8);

    // -------- gather phase: 16 rows into wave-private LDS --------
    unsigned short* arow = &ag[wv][0];
    int eo = lane >> 3, cg = lane & 7;
    for (int r = 0; r < 16; ++r) {
        int row = tile * 16 + r;
        int e0 = rowptr[row], e1 = rowptr[row + 1];
        float a[8];
#pragma unroll
        for (int k = 0; k < 8; ++k) a[k] = 0.0f;
        int j = e0;
        for (; j + 16 <= e1; j += 16) {
            int s0 = csr[j + eo];
            int s1 = csr[j + 8 + eo];
            ushort8v v0 = *reinterpret_cast<const ushort8v*>(
                evt_h + (size_t)s0 * 64 + cg * 8);
            ushort8v v1 = *reinterpret_cast<const ushort8v*>(
                evt_h + (size_t)s1 * 64 + cg * 8);
#pragma unroll
            for (int k = 0; k < 8; ++k) a[k] += b2f(v0[k]) + b2f(v1[k]);
        }
        for (; j < e1; j += 8) {
            int jj = j + eo;
            bool c = jj < e1;
            int s = csr[c ? jj : j];
            ushort8v v = *reinterpret_cast<const ushort8v*>(
                evt_h + (size_t)s * 64 + cg * 8);
            if (c) {
#pragma unroll
                for (int k = 0; k < 8; ++k) a[k] += b2f(v[k]);
            }
        }
#pragma unroll
        for (int k = 0; k < 8; ++k) {
            a[k] += __shfl_xor(a[k], 8);
            a[k] += __shfl_xor(a[k], 16);
            a[k] += __shfl_xor(a[k], 32);
        }
        float inv = (e1 > e0) ? 1.0f / (float)(e1 - e0) : 0.0f;
        if (eo == 0) {
            ushort8v o;
#pragma unroll
            for (int k = 0; k < 8; ++k) o[k] = f2b(a[k] * inv);
            *reinterpret_cast<ushort8v*>(arow + r * 72 + cg * 8) = o;
        }
    }
    // wave-private LDS: no barrier needed (compiler inserts lgkmcnt waits)

    // -------- head phase: A-frags from LDS --------
    short8 c[4];
#pragma unroll
    for (int kk = 0; kk < 2; ++kk) {
        c[kk] = *reinterpret_cast<const short8*>(
            arow + l15 * 72 + kk * 32 + quad * 8);
        c[2 + kk] = cl[kk];
    }

    floatx4 acc[4];
#pragma unroll
    for (int q = 0; q < 4; ++q) acc[q] = (floatx4)0.0f;
#pragma unroll
    for (int q = 0; q < 4; ++q) {
        short8 bwl[2], bwr[2];
#pragma unroll
        for (int kk = 0; kk < 2; ++kk) {
            bwl[kk] = *reinterpret_cast<const short8*>(
                &bls[((q * 2 + kk) * 64 + lane) * 8]);
            bwr[kk] = *reinterpret_cast<const short8*>(
                &brs[((q * 2 + kk) * 64 + lane) * 8]);
        }
#pragma unroll
        for (int kk = 0; kk < 2; ++kk) {
            acc[q] = __builtin_amdgcn_mfma_f32_16x16x32_bf16(
                c[kk], bwl[kk], acc[q], 0, 0, 0);
            acc[q] = __builtin_amdgcn_mfma_f32_16x16x32_bf16(
                c[2 + kk], bwr[kk], acc[q], 0, 0, 0);
        }
    }
#pragma unroll
    for (int q = 0; q < 4; ++q)
#pragma unroll
        for (int r = 0; r < 4; ++r) {
            float v = acc[q][r] + bbl[q];
            v = v > 0.0f ? v : 0.0f;
            h2s[wv][(quad * 4 + r) * 64 + q * 16 + l15] = f2b(v);
        }
    short8 aH[2];
#pragma unroll
    for (int kk = 0; kk < 2; ++kk)
        aH[kk] = *reinterpret_cast<const short8*>(
            &h2s[wv][l15 * 64 + kk * 32 + quad * 8]);

    floatx4 a1[2];
#pragma unroll
    for (int q = 0; q < 2; ++q) a1[q] = (floatx4)0.0f;
#pragma unroll
    for (int q = 0; q < 2; ++q) {
        short8 bw1[2];
#pragma unroll
        for (int kk = 0; kk < 2; ++kk)
            bw1[kk] = *reinterpret_cast<const short8*>(
                &b1s[((q * 2 + kk) * 64 + lane) * 8]);
#pragma unroll
        for (int kk = 0; kk < 2; ++kk)
            a1[q] = __builtin_amdgcn_mfma_f32_16x16x32_bf16(
                aH[kk], bw1[kk], a1[q], 0, 0, 0);
    }

    float s[4] = {0.f, 0.f, 0.f, 0.f};
#pragma unroll
    for (int q = 0; q < 2; ++q)
#pragma unroll
        for (int r = 0; r < 4; ++r) {
            float v = a1[q][r] + bh1v[q];
            v = v > 0.0f ? v : 0.0f;
            s[r] += v * w2v[q];
        }
#pragma unroll
    for (int r = 0; r < 4; ++r) {
        s[r] += __shfl_xor(s[r], 1);
        s[r] += __shfl_xor(s[r], 2);
        s[r] += __shfl_xor(s[r], 4);
        s[r] += __shfl_xor(s[r], 8);
    }
#pragma unroll
    for (int r = 0; r < 4; ++r) {
        if (l15 == r) {
            int row = tile * 16 + quad * 4 + r;
            float v = s[r] + bb2;
            if (fout) ((float*)out)[row] = v;
            else      ((unsigned short*)out)[row] = f2b(v);
        }
    }
}

// ---------------------------------------------------------------------------
// Workspace layout (bytes):
//   0:          evt_h    bf16 [200000,64] (25,600,000)
//   25600000:   loc_h    bf16 [100000,64] (12,800,000)
//   38400000:   csr      int [1M]         (4,000,000)
//   42400000:   rowptr   int [100001]     (400,016)
//   42800016:   gbc      int [256]        (1,024)
//   42802064:   wp_all   bf16 [26624]     (53,248)
//   42855312:   flags    int[16]          (64)
//   42855376:   bkt uint2[256][6000] (12,288,000)   (agg eliminated in R16)
// ---------------------------------------------------------------------------
extern "C" void kernel_launch(void* const* d_in, const int* in_sizes, int n_in,
                              void* d_out, int out_size, void* d_ws, size_t ws_size,
                              hipStream_t stream) {
    (void)in_sizes; (void)n_in; (void)out_size; (void)ws_size;
    const void* loc_x = d_in[0];
    const void* evt_x = d_in[1];
    const int*  eidx  = (const int*)d_in[2];
    const void* W_loc = d_in[3];
    const void* b_loc = d_in[4];
    const void* W_evt = d_in[5];
    const void* b_evt = d_in[6];
    const void* W_l   = d_in[7];
    const void* b_l   = d_in[8];
    const void* W_r   = d_in[9];
    const void* W_h1  = d_in[10];
    const void* b_h1  = d_in[11];
    const void* W_h2  = d_in[12];
    const void* b_h2  = d_in[13];

    char* ws = (char*)d_ws;
    unsigned short* evt_h  = (unsigned short*)(ws);
    unsigned short* loc_h  = (unsigned short*)(ws + 25600000);
    int*            csr    = (int*)(ws + 38400000);
    int*            rowptr = (int*)(ws + 42400000);
    int*            gbc    = (int*)(ws + 42800016);
    unsigned short* wp_all = (unsigned short*)(ws + 42802064);
    int*            flags  = (int*)(ws + 42855312);
    uint2*          bkt    = (uint2*)(ws + 42855376);

    prep_kernel<<<28, 256, 0, stream>>>(
        loc_x, evt_x, eidx, W_loc, b_loc, W_evt, b_evt,
        W_l, b_l, W_r, W_h1, b_h1, W_h2, b_h2,
        flags, gbc, wp_all);

    proj_both_kernel<<<PROJ_BLK_TOT, 256, 0, stream>>>(
        evt_x, loc_x, wp_all, b_evt, b_loc, evt_h, loc_h, flags);

    bucket_kernel<<<BKT_BLK, 256, 0, stream>>>(eidx, bkt, gbc, flags);
    csr_build_kernel<<<NBKT, 256, 0, stream>>>(bkt, gbc, rowptr, csr);

    agg_head_kernel<<<AGGH_BLK, 256, 0, stream>>>(
        evt_h, loc_h, rowptr, csr, wp_all,
        b_l, b_h1, W_h2, b_h2, d_out, flags);
}

// Round 12
// 299.921 us; speedup vs baseline: 1.0971x; 1.0971x over previous
//
#include <hip/hip_runtime.h>

// ---------------------------------------------------------------------------
// HeteroGNN fused pipeline for MI355X (gfx950).
//   loc_h = relu(loc_x @ W_loc + b_loc)          [100000, 64]
//   evt_h = relu(evt_x @ W_evt + b_evt)          [200000, 64]
//   agg   = segment_mean(evt_h[src] -> dst)      (bucketed CSR gather)
//   h2    = relu(agg @ W_l + b_l + loc_h @ W_r)  (MFMA)
//   h1    = relu(h2 @ W_h1 + b_h1)               (MFMA)
//   out   = h1 @ W_h2 + b_h2                     [100000]
// Proj verdict (R6-R15): pinned 66-72us, 2.9TB/s demand-side. bounds(256,4)
//   => 64-VGPR spill (NEVER). Contiguous ranges lose L3 (keep strided).
//   Proj DONE at bounds(256,3)+strided+LDS-B, grid 1536+768.
// R16 (measured): agg+head fusion REGRESSED (329 vs 300.6): gather became
//   16-row serial per wave (16x less parallelism), latency-exposed.
//   By-product attribution: agg+head separate ~45us, proj 66 => bucket+csr
//   ~180us hidden under the top-5 threshold. They are latency-bound
//   (36MB traffic ~= 15us at BW): csr_build = 1 blk/CU = 4 waves/CU.
// R18: revert fusion (R15 split restored); bucket + csr_build go to
//   512-thread blocks (8 waves each -> 2x wave parallelism on the
//   latency-chained loops, half the barrier rounds). Algorithms unchanged.
// ---------------------------------------------------------------------------

#define N_LOC 100000
#define N_EVT 200000
#define E_CNT 1000000
#define NTILES 6250   // N_LOC / 16
#define NBKT   256
#define BKT_L  391    // locations per bucket (255*391=99705 <= 99999)
#define CAPG   6000   // per-bucket capacity (avg 3906, sigma 62 -> +33 sigma)
#define QCAP   32     // passA LDS queue depth per bucket
#define BKT_BLK 512   // passA blocks (2 per CU at 64KB LDS)
#define PERB   1954   // edges per passA block (512*1954 >= 1e6)

#define PROJ_EVT_BLK 1536
#define PROJ_LOC_BLK 768
#define PROJ_BLK_TOT (PROJ_EVT_BLK + PROJ_LOC_BLK)
#define EVT_TILES 12500   // 200000/16
#define LOC_TILES 6250    // 100000/16
#define HEAD_BLK  1024

typedef __attribute__((ext_vector_type(8))) short short8;   // 8 x bf16
typedef __attribute__((ext_vector_type(4))) float floatx4;  // MFMA C/D frag
typedef __attribute__((ext_vector_type(8))) unsigned short ushort8v;

__device__ __forceinline__ float b2f(unsigned short u) {
    unsigned int x = ((unsigned int)u) << 16;
    return __builtin_bit_cast(float, x);
}
__device__ __forceinline__ unsigned short f2b(float f) {
    unsigned int x = __builtin_bit_cast(unsigned int, f);
    unsigned int r = (x + 0x7fffu + ((x >> 16) & 1u)) >> 16;  // RNE
    return (unsigned short)r;
}
__device__ __forceinline__ float loadf(const void* p, int f32, size_t i) {
    return f32 ? ((const float*)p)[i] : b2f(((const unsigned short*)p)[i]);
}

// ---------------------------------------------------------------------------
// KA: detect + zero + permute, one launch, 28 blocks.
// wp_all offsets (elements): evt 0, loc 8192, W_l 16384, W_r 20480, W_h1 24576
// ---------------------------------------------------------------------------
__global__ __launch_bounds__(256) void prep_kernel(
    const void* t0, const void* t1, const int* eidx,
    const void* t3, const void* t4, const void* t5, const void* t6,
    const void* t7, const void* t8, const void* t9, const void* t10,
    const void* t11, const void* t12, const void* t13,
    int* flags, int* gbc, unsigned short* __restrict__ wp_all) {
    int b = blockIdx.x, tid = threadIdx.x;
    __shared__ int s0, s1;

    if (b == 14) { gbc[tid] = 0; return; }

    if (b >= 15) {                           // permute, self-detecting
        int pb = b - 15;
        const void* W; int K, N, bstart, off;
        if (pb < 4)       { W = t5;  K = 128; N = 64; bstart = 0;  off = 0; }
        else if (pb < 8)  { W = t3;  K = 128; N = 64; bstart = 4;  off = 8192; }
        else if (pb < 10) { W = t7;  K = 64;  N = 64; bstart = 8;  off = 16384; }
        else if (pb < 12) { W = t9;  K = 64;  N = 64; bstart = 10; off = 20480; }
        else              { W = t10; K = 64;  N = 32; bstart = 12; off = 24576; }
        if (tid == 0) s0 = 0;
        __syncthreads();
        int nsamp = 2 * K * N; if (nsamp > 1024) nsamp = 1024;
        const unsigned short* h = (const unsigned short*)W;
        int susp = 0;
        for (int i = tid; i < nsamp; i += 256)
            if (((h[i] >> 7) & 0xFF) >= 0x90) susp++;
        if (susp) atomicAdd(&s0, susp);
        __syncthreads();
        int f32 = (s0 * 16 >= nsamp) ? 1 : 0;

        int idx  = (pb - bstart) * 256 + tid;
        int nk   = K >> 5;
        int f    = idx >> 6;
        int lane = idx & 63;
        int t  = f / nk;
        int kk = f - t * nk;
        int n  = t * 16 + (lane & 15);
        int k0 = kk * 32 + (lane >> 4) * 8;
        unsigned short tmp[8];
#pragma unroll
        for (int j = 0; j < 8; ++j) {
            size_t src = (size_t)(k0 + j) * N + n;
            tmp[j] = f32 ? f2b(((const float*)W)[src])
                         : ((const unsigned short*)W)[src];
        }
#pragma unroll
        for (int j = 0; j < 8; ++j) wp_all[(size_t)off + (size_t)idx * 8 + j] = tmp[j];
        return;
    }

    if (tid == 0) { s0 = 0; s1 = 0; }
    __syncthreads();
    if (b == 13) {   // edge_index: int64 => all odd 32-bit words zero
        if (tid < 128) {
            if (eidx[2 * tid] != 0) atomicAdd(&s0, 1);
            if (eidx[2 * tid + 1] != 0) atomicAdd(&s1, 1);
        }
        __syncthreads();
        if (tid == 0) flags[2] = (s1 == 0 && s0 > 32) ? 1 : 0;
        return;
    }
    const void* ptrs[13] = {t0, t1, t3, t4, t5, t6, t7, t8, t9, t10, t11, t12, t13};
    const int   cnts[13] = {12800000, 25600000, 8192, 64, 8192, 64,
                            4096, 64, 4096, 2048, 32, 32, 1};
    const int   slot[13] = {0, 1, 3, 4, 5, 6, 7, 8, 9, 10, 11, 12, 13};
    int nsamp = 2 * cnts[b];
    if (nsamp > 1024) nsamp = 1024;
    const unsigned short* h = (const unsigned short*)ptrs[b];
    int susp = 0;
    for (int i = tid; i < nsamp; i += 256)
        if (((h[i] >> 7) & 0xFF) >= 0x90) susp++;
    if (susp) atomicAdd(&s0, susp);
    __syncthreads();
    if (tid == 0) flags[slot[b]] = (s0 * 16 >= nsamp) ? 1 : 0;
}

// ---------------------------------------------------------------------------
// K1: both projections. R10 inner loop (strided tiles, 1-deep prefetch,
// split fx paths, LDS-B), bounds(256,3), grid 1536+768. PROVEN CONFIG.
// ---------------------------------------------------------------------------
__global__ __launch_bounds__(256, 3) void proj_both_kernel(
    const void* __restrict__ evt_x, const void* __restrict__ loc_x,
    const unsigned short* __restrict__ wp_all,
    const void* __restrict__ b_evt, const void* __restrict__ b_loc,
    unsigned short* __restrict__ evt_h, unsigned short* __restrict__ loc_h,
    const int* __restrict__ flags) {
    __shared__ unsigned short bs[8192];   // 16 KB: B in MFMA frag order
    int blk = blockIdx.x;
    int tid = threadIdx.x, lane = tid & 63, wv = tid >> 6;
    int l15 = lane & 15, quad = lane >> 4;

    const void* X; const unsigned short* Wp; const void* bias;
    unsigned short* Y; int fx, fb, w0, nw, ntile;
    if (blk < PROJ_EVT_BLK) {
        X = evt_x; Wp = wp_all;        bias = b_evt; Y = evt_h;
        fx = flags[1]; fb = flags[6];
        w0 = blk * 4 + wv; nw = PROJ_EVT_BLK * 4; ntile = EVT_TILES;
    } else {
        X = loc_x; Wp = wp_all + 8192; bias = b_loc; Y = loc_h;
        fx = flags[0]; fb = flags[4];
        w0 = (blk - PROJ_EVT_BLK) * 4 + wv; nw = PROJ_LOC_BLK * 4; ntile = LOC_TILES;
    }

    // cooperative B stage: 1024 x short8, coalesced
    {
        const short8* src = reinterpret_cast<const short8*>(Wp);
        short8* dst = reinterpret_cast<short8*>(bs);
#pragma unroll
        for (int i = 0; i < 4; ++i) dst[tid + i * 256] = src[tid + i * 256];
    }
    __syncthreads();

    float bv[4];
#pragma unroll
    for (int q = 0; q < 4; ++q) bv[q] = loadf(bias, fb, q * 16 + l15);

    if (w0 >= ntile) return;

    // shared epilogue: LDS-B MFMA + bias/relu/store
    auto mfma_store = [&](const short8* a, int t) {
        floatx4 acc[4];
#pragma unroll
        for (int q = 0; q < 4; ++q) acc[q] = (floatx4)0.0f;
#pragma unroll
        for (int q = 0; q < 4; ++q) {
            short8 bq[4];
#pragma unroll
            for (int kk = 0; kk < 4; ++kk)
                bq[kk] = *reinterpret_cast<const short8*>(
                    &bs[((q * 4 + kk) * 64 + lane) * 8]);
#pragma unroll
            for (int kk = 0; kk < 4; ++kk)
                acc[q] = __builtin_amdgcn_mfma_f32_16x16x32_bf16(
                    a[kk], bq[kk], acc[q], 0, 0, 0);
        }
#pragma unroll
        for (int q = 0; q < 4; ++q)
#pragma unroll
            for (int r = 0; r < 4; ++r) {
                float v = acc[q][r] + bv[q];
                v = v > 0.0f ? v : 0.0f;
                Y[(size_t)(t * 16 + quad * 4 + r) * 64 + q * 16 + l15] = f2b(v);
            }
    };

    if (fx) {
        // --- fp32 input path: only pf[8] staging live (32 VGPRs) ---
        const float* Xf = (const float*)X;
        float4 pf[8];
        auto issueF = [&](int t) {
            const float* xr = Xf + (size_t)(t * 16 + l15) * 128 + quad * 8;
#pragma unroll
            for (int kk = 0; kk < 4; ++kk) {
                pf[kk * 2]     = *reinterpret_cast<const float4*>(xr + kk * 32);
                pf[kk * 2 + 1] = *reinterpret_cast<const float4*>(xr + kk * 32 + 4);
            }
        };
        issueF(w0);
        for (int t = w0; t < ntile; t += nw) {
            short8 a[4];
#pragma unroll
            for (int kk = 0; kk < 4; ++kk) {
                float4 p0 = pf[kk * 2], p1 = pf[kk * 2 + 1];
                short8 v;
                v[0] = (short)f2b(p0.x); v[1] = (short)f2b(p0.y);
                v[2] = (short)f2b(p0.z); v[3] = (short)f2b(p0.w);
                v[4] = (short)f2b(p1.x); v[5] = (short)f2b(p1.y);
                v[6] = (short)f2b(p1.z); v[7] = (short)f2b(p1.w);
                a[kk] = v;
            }
            int tn = t + nw;
            if (tn < ntile) issueF(tn);   // next tile in flight during MFMA+store
            mfma_store(a, t);
        }
    } else {
        // --- bf16 input path: only an[4] staging live (16 VGPRs) ---
        const unsigned short* Xh = (const unsigned short*)X;
        short8 an[4];
        auto issueH = [&](int t) {
            const unsigned short* xr = Xh + (size_t)(t * 16 + l15) * 128 + quad * 8;
#pragma unroll
            for (int kk = 0; kk < 4; ++kk)
                an[kk] = *reinterpret_cast<const short8*>(xr + kk * 32);
        };
        issueH(w0);
        for (int t = w0; t < ntile; t += nw) {
            short8 a[4];
#pragma unroll
            for (int kk = 0; kk < 4; ++kk) a[kk] = an[kk];
            int tn = t + nw;
            if (tn < ntile) issueH(tn);
            mfma_store(a, t);
        }
    }
}

// ---------------------------------------------------------------------------
// K2a (R18): bucket edges by dst/391 via LDS queues; 512-thread blocks
// (8 waves -> 16 waves/CU at 2 blocks/CU). Push stride 512, 4 rounds.
// Flush phase: first 256 threads own one bucket each (unchanged logic).
// ---------------------------------------------------------------------------
__global__ __launch_bounds__(512) void bucket_kernel(
    const int* __restrict__ eidx, uint2* __restrict__ bkt,
    int* __restrict__ gbc, const int* __restrict__ flags) {
    __shared__ uint2 queue[NBKT][QCAP];   // 64 KB
    __shared__ int qcnt[NBKT];
    int tid = threadIdx.x, blk = blockIdx.x;
    if (tid < NBKT) qcnt[tid] = 0;
    __syncthreads();
    int f64 = flags[2];
    const long long* e64 = (const long long*)eidx;
    int e0 = blk * PERB;
    int e1 = e0 + PERB; if (e1 > E_CNT) e1 = E_CNT;
    const int rounds = (PERB + 511) / 512;

    for (int r = 0; r < rounds; ++r) {
        int e = e0 + r * 512 + tid;
        if (e < e1) {
            int src, dst;
            if (f64) { src = (int)e64[e]; dst = (int)e64[E_CNT + e]; }
            else     { src = eidx[e];     dst = eidx[E_CNT + e]; }
            if ((unsigned)dst < (unsigned)N_LOC && (unsigned)src < (unsigned)N_EVT) {
                int bk = dst / BKT_L;
                int pos = atomicAdd(&qcnt[bk], 1);
                if (pos < QCAP) {
                    queue[bk][pos] = make_uint2((unsigned)src, (unsigned)dst);
                } else {   // overflow (astronomically rare): direct store
                    int p = atomicAdd(&gbc[bk], 1);
                    if (p < CAPG) bkt[(size_t)bk * CAPG + p] = make_uint2(src, dst);
                }
            }
        }
        __syncthreads();
        // flush phase: thread t (t<256) owns bucket t
        if (tid < NBKT) {
            int n = qcnt[tid]; if (n > QCAP) n = QCAP;
            while (n >= 16) {
                int gp = atomicAdd(&gbc[tid], 16);
                if (gp + 16 <= CAPG) {
                    uint2* d = bkt + (size_t)tid * CAPG + gp;
#pragma unroll
                    for (int j = 0; j < 16; ++j) d[j] = queue[tid][j];
                }
#pragma unroll
                for (int j = 16; j < QCAP; ++j) queue[tid][j - 16] = queue[tid][j];
                n -= 16;
            }
            qcnt[tid] = n;
        }
        __syncthreads();
    }
    // tail flush
    if (tid < NBKT) {
        int n = qcnt[tid]; if (n > QCAP) n = QCAP;
        if (n > 0) {
            int gp = atomicAdd(&gbc[tid], n);
            for (int j = 0; j < n; ++j)
                if (gp + j < CAPG) bkt[(size_t)tid * CAPG + gp + j] = queue[tid][j];
        }
    }
}

// ---------------------------------------------------------------------------
// K2c (R18): per-bucket local CSR build, 512-thread blocks (8 waves/CU vs
// 4 before -- the latency-chained count/scatter loops halve in iterations).
// gbc scan fused (first 256 threads). All global writes coalesced.
// ---------------------------------------------------------------------------
__global__ __launch_bounds__(512) void csr_build_kernel(
    const uint2* __restrict__ bkt, const int* __restrict__ gbc,
    int* __restrict__ rowptr, int* __restrict__ csr) {
    __shared__ int sg[256];
    __shared__ int lcnt[512];
    __shared__ int lscan[512];
    __shared__ int lcsr[CAPG];
    int b = blockIdx.x, tid = threadIdx.x;
    int loc0 = b * BKT_L;
    int nloc = N_LOC - loc0; if (nloc > BKT_L) nloc = BKT_L;

    // fused exclusive scan of clamped gbc (first 256 threads; all hit barriers)
    if (tid < 256) {
        int gv = gbc[tid]; if (gv > CAPG) gv = CAPG;
        sg[tid] = gv;
    }
    __syncthreads();
    for (int d = 1; d < 256; d <<= 1) {
        int x = (tid < 256 && tid >= d) ? sg[tid - d] : 0;
        __syncthreads();
        if (tid < 256) sg[tid] += x;
        __syncthreads();
    }
    int cntE = gbc[b]; if (cntE > CAPG) cntE = CAPG;
    int base = sg[b] - cntE;          // exclusive prefix
    const uint2* bp = bkt + (size_t)b * CAPG;

    lcnt[tid] = 0;
    __syncthreads();
    // count (512-thread stride)
    for (int i = tid; i < cntE; i += 512) {
        int d = (int)bp[i].y - loc0;
        atomicAdd(&lcnt[d], 1);
    }
    __syncthreads();
    // inclusive scan over 512 (Hillis-Steele, 1 elem/thread)
    lscan[tid] = lcnt[tid];
    __syncthreads();
    for (int d = 1; d < 512; d <<= 1) {
        int v = (tid >= d) ? lscan[tid - d] : 0;
        __syncthreads();
        lscan[tid] += v;
        __syncthreads();
    }
    // rowptr (exclusive) + reset lcnt to cursor start
    for (int i = tid; i < nloc; i += 512) {
        int excl = lscan[i] - lcnt[i];
        rowptr[loc0 + i] = base + excl;
        lcnt[i] = excl;
    }
    if (b == NBKT - 1 && tid == 0) rowptr[N_LOC] = base + cntE;
    __syncthreads();
    // scatter into LDS csr segment
    for (int i = tid; i < cntE; i += 512) {
        uint2 pr = bp[i];
        int d = (int)pr.y - loc0;
        int p = atomicAdd(&lcnt[d], 1);
        if (p < CAPG) lcsr[p] = (int)pr.x;
    }
    __syncthreads();
    // contiguous flush
    for (int i = tid; i < cntE; i += 512) csr[base + i] = lcsr[i];
}

// ---------------------------------------------------------------------------
// K3: gather-mean, 1 wave per row (100K waves -- parallelism is the point;
// R16's fused 16-row-serial variant measured 73us and regressed). lane =
// (edge eo = lane>>3) x (col-group cg = lane&7, 16B). One VMEM gathers 8
// full 128B rows; 2-deep unroll -> 16 rows in flight per wave.
// ---------------------------------------------------------------------------
__global__ __launch_bounds__(256) void aggregate_kernel(
    const unsigned short* __restrict__ evt_h,
    const int* __restrict__ rowptr, const int* __restrict__ csr,
    unsigned short* __restrict__ agg, int N) {
    int wid  = (blockIdx.x * 256 + threadIdx.x) >> 6;
    int lane = threadIdx.x & 63;
    int eo = lane >> 3, cg = lane & 7;
    if (wid >= N) return;
    int e0 = rowptr[wid], e1 = rowptr[wid + 1];
    float a[8];
#pragma unroll
    for (int k = 0; k < 8; ++k) a[k] = 0.0f;

    int j = e0;
    for (; j + 16 <= e1; j += 16) {
        int s0 = csr[j + eo];
        int s1 = csr[j + 8 + eo];
        ushort8v v0 = *reinterpret_cast<const ushort8v*>(
            evt_h + (size_t)s0 * 64 + cg * 8);
        ushort8v v1 = *reinterpret_cast<const ushort8v*>(
            evt_h + (size_t)s1 * 64 + cg * 8);
#pragma unroll
        for (int k = 0; k < 8; ++k) a[k] += b2f(v0[k]) + b2f(v1[k]);
    }
    for (; j < e1; j += 8) {
        int jj = j + eo;
        bool c = jj < e1;
        int s = csr[c ? jj : j];
        ushort8v v = *reinterpret_cast<const ushort8v*>(
            evt_h + (size_t)s * 64 + cg * 8);
        if (c) {
#pragma unroll
            for (int k = 0; k < 8; ++k) a[k] += b2f(v[k]);
        }
    }
    // reduce across the 8 eo-groups (lanes differing in bits 3..5)
#pragma unroll
    for (int k = 0; k < 8; ++k) {
        a[k] += __shfl_xor(a[k], 8);
        a[k] += __shfl_xor(a[k], 16);
        a[k] += __shfl_xor(a[k], 32);
    }
    float inv = (e1 > e0) ? 1.0f / (float)(e1 - e0) : 0.0f;
    if (eo == 0) {   // lanes 0..7 write 8 x 16B = 128B coalesced
        ushort8v o;
#pragma unroll
        for (int k = 0; k < 8; ++k) o[k] = f2b(a[k] * inv);
        *reinterpret_cast<ushort8v*>(agg + (size_t)wid * 64 + cg * 8) = o;
    }
}

// ---------------------------------------------------------------------------
// K4: SAGE + head via MFMA, persistent waves, three B matrices in LDS
// (20 KB + 8 KB h2s). 1024 blocks, strided. PROVEN (R15).
// ---------------------------------------------------------------------------
__global__ __launch_bounds__(256, 3) void head_kernel(
    const unsigned short* __restrict__ agg,
    const unsigned short* __restrict__ loc_h,
    const unsigned short* __restrict__ wp_all,
    const void* __restrict__ bl, const void* __restrict__ bh1,
    const void* __restrict__ wh2, const void* __restrict__ bh2,
    void* __restrict__ out, const int* __restrict__ flags) {
    __shared__ unsigned short bls[4096];  // W_l frags, 8 KB
    __shared__ unsigned short brs[4096];  // W_r frags, 8 KB
    __shared__ unsigned short b1s[2048];  // W_h1 frags, 4 KB
    __shared__ unsigned short h2s[4][16 * 64];
    int tid = threadIdx.x, lane = tid & 63, wv = tid >> 6;
    int l15 = lane & 15, quad = lane >> 4;
    int fbl = flags[8], fbh1 = flags[11], fwh2 = flags[12], fbh2 = flags[13];
    int fout = flags[0];
    const unsigned short* wp_l  = wp_all + 16384;
    const unsigned short* wp_r  = wp_all + 20480;
    const unsigned short* wp_h1 = wp_all + 24576;

    {   // cooperative stage: coalesced short8 copies
        const short8* sl = reinterpret_cast<const short8*>(wp_l);
        const short8* sr = reinterpret_cast<const short8*>(wp_r);
        const short8* s1 = reinterpret_cast<const short8*>(wp_h1);
        short8* dl = reinterpret_cast<short8*>(bls);
        short8* dr = reinterpret_cast<short8*>(brs);
        short8* d1 = reinterpret_cast<short8*>(b1s);
        dl[tid] = sl[tid]; dl[tid + 256] = sl[tid + 256];
        dr[tid] = sr[tid]; dr[tid + 256] = sr[tid + 256];
        d1[tid] = s1[tid];
    }
    __syncthreads();

    float bbl[4], bh1v[2], w2v[2];
#pragma unroll
    for (int q = 0; q < 4; ++q) bbl[q] = loadf(bl, fbl, q * 16 + l15);
#pragma unroll
    for (int q = 0; q < 2; ++q) {
        bh1v[q] = loadf(bh1, fbh1, q * 16 + l15);
        w2v[q]  = loadf(wh2, fwh2, q * 16 + l15);
    }
    float bb2 = loadf(bh2, fbh2, 0);

    const int NW = HEAD_BLK * 4;   // 4096 waves
    int w0 = blockIdx.x * 4 + wv;
    if (w0 >= NTILES) return;

    short8 c0[4], c1[4];   // [0..1]=agg frags, [2..3]=loc_h frags

    auto issue = [&](short8* c, int t) {
        int m = t * 16 + l15;
#pragma unroll
        for (int kk = 0; kk < 2; ++kk) {
            c[kk]     = *reinterpret_cast<const short8*>(
                agg + (size_t)m * 64 + kk * 32 + quad * 8);
            c[2 + kk] = *reinterpret_cast<const short8*>(
                loc_h + (size_t)m * 64 + kk * 32 + quad * 8);
        }
    };

    auto compute = [&](const short8* c, int tile) {
        floatx4 acc[4];
#pragma unroll
        for (int q = 0; q < 4; ++q) acc[q] = (floatx4)0.0f;
#pragma unroll
        for (int q = 0; q < 4; ++q) {
            short8 bwl[2], bwr[2];
#pragma unroll
            for (int kk = 0; kk < 2; ++kk) {
                bwl[kk] = *reinterpret_cast<const short8*>(
                    &bls[((q * 2 + kk) * 64 + lane) * 8]);
                bwr[kk] = *reinterpret_cast<const short8*>(
                    &brs[((q * 2 + kk) * 64 + lane) * 8]);
            }
#pragma unroll
            for (int kk = 0; kk < 2; ++kk) {
                acc[q] = __builtin_amdgcn_mfma_f32_16x16x32_bf16(
                    c[kk], bwl[kk], acc[q], 0, 0, 0);
                acc[q] = __builtin_amdgcn_mfma_f32_16x16x32_bf16(
                    c[2 + kk], bwr[kk], acc[q], 0, 0, 0);
            }
        }
#pragma unroll
        for (int q = 0; q < 4; ++q)
#pragma unroll
            for (int r = 0; r < 4; ++r) {
                float v = acc[q][r] + bbl[q];
                v = v > 0.0f ? v : 0.0f;
                h2s[wv][(quad * 4 + r) * 64 + q * 16 + l15] = f2b(v);
            }
        short8 aH[2];
#pragma unroll
        for (int kk = 0; kk < 2; ++kk)
            aH[kk] = *reinterpret_cast<const short8*>(
                &h2s[wv][l15 * 64 + kk * 32 + quad * 8]);

        floatx4 a1[2];
#pragma unroll
        for (int q = 0; q < 2; ++q) a1[q] = (floatx4)0.0f;
#pragma unroll
        for (int q = 0; q < 2; ++q) {
            short8 bw1[2];
#pragma unroll
            for (int kk = 0; kk < 2; ++kk)
                bw1[kk] = *reinterpret_cast<const short8*>(
                    &b1s[((q * 2 + kk) * 64 + lane) * 8]);
#pragma unroll
            for (int kk = 0; kk < 2; ++kk)
                a1[q] = __builtin_amdgcn_mfma_f32_16x16x32_bf16(
                    aH[kk], bw1[kk], a1[q], 0, 0, 0);
        }

        float s[4] = {0.f, 0.f, 0.f, 0.f};
#pragma unroll
        for (int q = 0; q < 2; ++q)
#pragma unroll
            for (int r = 0; r < 4; ++r) {
                float v = a1[q][r] + bh1v[q];
                v = v > 0.0f ? v : 0.0f;
                s[r] += v * w2v[q];
            }
#pragma unroll
        for (int r = 0; r < 4; ++r) {
            s[r] += __shfl_xor(s[r], 1);
            s[r] += __shfl_xor(s[r], 2);
            s[r] += __shfl_xor(s[r], 4);
            s[r] += __shfl_xor(s[r], 8);
        }
#pragma unroll
        for (int r = 0; r < 4; ++r) {
            if (l15 == r) {
                int row = tile * 16 + quad * 4 + r;
                float v = s[r] + bb2;
                if (fout) ((float*)out)[row] = v;
                else      ((unsigned short*)out)[row] = f2b(v);
            }
        }
    };

    issue(c0, w0);
    int t = w0;
    while (true) {
        int tn = t + NW;
        bool hn = tn < NTILES;
        if (hn) issue(c1, tn);
        compute(c0, t);
        if (!hn) break;
        t = tn; tn = t + NW; hn = tn < NTILES;
        if (hn) issue(c0, tn);
        compute(c1, t);
        if (!hn) break;
        t = tn;
    }
}

// ---------------------------------------------------------------------------
// Workspace layout (bytes):
//   0:          evt_h    bf16 [200000,64] (25,600,000)
//   25600000:   loc_h    bf16 [100000,64] (12,800,000)
//   38400000:   csr      int [1M]         (4,000,000)
//   42400000:   rowptr   int [100001]     (400,016)
//   42800016:   gbc      int [256]        (1,024)
//   42802064:   wp_all   bf16 [26624]     (53,248)
//   42855312:   flags    int[16]          (64)
//   42855376:   bkt uint2[256][6000] (12,288,000) / agg bf16 (12,800,000)
//               (temporally disjoint: bkt dead after csr_build)
// ---------------------------------------------------------------------------
extern "C" void kernel_launch(void* const* d_in, const int* in_sizes, int n_in,
                              void* d_out, int out_size, void* d_ws, size_t ws_size,
                              hipStream_t stream) {
    (void)in_sizes; (void)n_in; (void)out_size; (void)ws_size;
    const void* loc_x = d_in[0];
    const void* evt_x = d_in[1];
    const int*  eidx  = (const int*)d_in[2];
    const void* W_loc = d_in[3];
    const void* b_loc = d_in[4];
    const void* W_evt = d_in[5];
    const void* b_evt = d_in[6];
    const void* W_l   = d_in[7];
    const void* b_l   = d_in[8];
    const void* W_r   = d_in[9];
    const void* W_h1  = d_in[10];
    const void* b_h1  = d_in[11];
    const void* W_h2  = d_in[12];
    const void* b_h2  = d_in[13];

    char* ws = (char*)d_ws;
    unsigned short* evt_h  = (unsigned short*)(ws);
    unsigned short* loc_h  = (unsigned short*)(ws + 25600000);
    int*            csr    = (int*)(ws + 38400000);
    int*            rowptr = (int*)(ws + 42400000);
    int*            gbc    = (int*)(ws + 42800016);
    unsigned short* wp_all = (unsigned short*)(ws + 42802064);
    int*            flags  = (int*)(ws + 42855312);
    uint2*          bkt    = (uint2*)(ws + 42855376);
    unsigned short* agg    = (unsigned short*)(ws + 42855376);

    prep_kernel<<<28, 256, 0, stream>>>(
        loc_x, evt_x, eidx, W_loc, b_loc, W_evt, b_evt,
        W_l, b_l, W_r, W_h1, b_h1, W_h2, b_h2,
        flags, gbc, wp_all);

    proj_both_kernel<<<PROJ_BLK_TOT, 256, 0, stream>>>(
        evt_x, loc_x, wp_all, b_evt, b_loc, evt_h, loc_h, flags);

    bucket_kernel<<<BKT_BLK, 512, 0, stream>>>(eidx, bkt, gbc, flags);
    csr_build_kernel<<<NBKT, 512, 0, stream>>>(bkt, gbc, rowptr, csr);

    aggregate_kernel<<<(N_LOC + 3) / 4, 256, 0, stream>>>(evt_h, rowptr, csr,
                                                          agg, N_LOC);

    head_kernel<<<HEAD_BLK, 256, 0, stream>>>(
        agg, loc_h, wp_all, b_l, b_h1, W_h2, b_h2, d_out, flags);
}

// Round 14
// 287.037 us; speedup vs baseline: 1.1464x; 1.0449x over previous
//
#include <hip/hip_runtime.h>

// ---------------------------------------------------------------------------
// HeteroGNN fused pipeline for MI355X (gfx950).
//   loc_h = relu(loc_x @ W_loc + b_loc)          [100000, 64]
//   evt_h = relu(evt_x @ W_evt + b_evt)          [200000, 64]
//   agg   = segment_mean(evt_h[src] -> dst)      (bucketed CSR gather)
//   h2    = relu(agg @ W_l + b_l + loc_h @ W_r)  (MFMA)
//   h1    = relu(h2 @ W_h1 + b_h1)               (MFMA)
//   out   = h1 @ W_h2 + b_h2                     [100000]
// Proj verdict (R6-R15): pinned 66-72us, ~2.9TB/s demand-side, occupancy
//   pinned ~2 blocks/CU. bounds(256,4) => spill (NEVER). Keep strided order.
// R16 (measured): agg+head fusion regressed (serial gather). agg+head ~45us.
// R18 (measured): 512-thread bucket/csr NULL (299.9 vs 300.6) -> the hidden
//   ~190us (prep+bucket+csr by subtraction) doesn't respond to waves/block.
// R19: exploit the DEPENDENCY GRAPH instead: bucket is independent of proj
//   (disjoint inputs/outputs). Fuse into one kernel, 2816 blocks interleaved
//   9:2 per 11 (2304 proj + 512 bucket, spread through dispatch order).
//   LDS union = bucket's 65.5KB -> 2 blocks/CU = proj's measured residency
//   anyway. Both paths bit-exact R15 code. bucket hides under proj.
// R20: identical to R19 (R19 bench was a GPUAcquisitionTimeout, never ran).
// ---------------------------------------------------------------------------

#define N_LOC 100000
#define N_EVT 200000
#define E_CNT 1000000
#define NTILES 6250   // N_LOC / 16
#define NBKT   256
#define BKT_L  391    // locations per bucket (255*391=99705 <= 99999)
#define CAPG   6000   // per-bucket capacity (avg 3906, sigma 62 -> +33 sigma)
#define QCAP   32     // passA LDS queue depth per bucket
#define BKT_BLK 512   // bucket sub-blocks
#define PERB   1954   // edges per bucket block (512*1954 >= 1e6)

#define PROJ_EVT_BLK 1536
#define PROJ_LOC_BLK 768
#define PROJ_BLK_TOT (PROJ_EVT_BLK + PROJ_LOC_BLK)   // 2304
#define PB_TOT (PROJ_BLK_TOT + BKT_BLK)              // 2816 = 256*11
#define EVT_TILES 12500   // 200000/16
#define LOC_TILES 6250    // 100000/16
#define HEAD_BLK  1024

typedef __attribute__((ext_vector_type(8))) short short8;   // 8 x bf16
typedef __attribute__((ext_vector_type(4))) float floatx4;  // MFMA C/D frag
typedef __attribute__((ext_vector_type(8))) unsigned short ushort8v;

__device__ __forceinline__ float b2f(unsigned short u) {
    unsigned int x = ((unsigned int)u) << 16;
    return __builtin_bit_cast(float, x);
}
__device__ __forceinline__ unsigned short f2b(float f) {
    unsigned int x = __builtin_bit_cast(unsigned int, f);
    unsigned int r = (x + 0x7fffu + ((x >> 16) & 1u)) >> 16;  // RNE
    return (unsigned short)r;
}
__device__ __forceinline__ float loadf(const void* p, int f32, size_t i) {
    return f32 ? ((const float*)p)[i] : b2f(((const unsigned short*)p)[i]);
}

// ---------------------------------------------------------------------------
// KA: detect + zero + permute, one launch, 28 blocks.
// wp_all offsets (elements): evt 0, loc 8192, W_l 16384, W_r 20480, W_h1 24576
// ---------------------------------------------------------------------------
__global__ __launch_bounds__(256) void prep_kernel(
    const void* t0, const void* t1, const int* eidx,
    const void* t3, const void* t4, const void* t5, const void* t6,
    const void* t7, const void* t8, const void* t9, const void* t10,
    const void* t11, const void* t12, const void* t13,
    int* flags, int* gbc, unsigned short* __restrict__ wp_all) {
    int b = blockIdx.x, tid = threadIdx.x;
    __shared__ int s0, s1;

    if (b == 14) { gbc[tid] = 0; return; }

    if (b >= 15) {                           // permute, self-detecting
        int pb = b - 15;
        const void* W; int K, N, bstart, off;
        if (pb < 4)       { W = t5;  K = 128; N = 64; bstart = 0;  off = 0; }
        else if (pb < 8)  { W = t3;  K = 128; N = 64; bstart = 4;  off = 8192; }
        else if (pb < 10) { W = t7;  K = 64;  N = 64; bstart = 8;  off = 16384; }
        else if (pb < 12) { W = t9;  K = 64;  N = 64; bstart = 10; off = 20480; }
        else              { W = t10; K = 64;  N = 32; bstart = 12; off = 24576; }
        if (tid == 0) s0 = 0;
        __syncthreads();
        int nsamp = 2 * K * N; if (nsamp > 1024) nsamp = 1024;
        const unsigned short* h = (const unsigned short*)W;
        int susp = 0;
        for (int i = tid; i < nsamp; i += 256)
            if (((h[i] >> 7) & 0xFF) >= 0x90) susp++;
        if (susp) atomicAdd(&s0, susp);
        __syncthreads();
        int f32 = (s0 * 16 >= nsamp) ? 1 : 0;

        int idx  = (pb - bstart) * 256 + tid;
        int nk   = K >> 5;
        int f    = idx >> 6;
        int lane = idx & 63;
        int t  = f / nk;
        int kk = f - t * nk;
        int n  = t * 16 + (lane & 15);
        int k0 = kk * 32 + (lane >> 4) * 8;
        unsigned short tmp[8];
#pragma unroll
        for (int j = 0; j < 8; ++j) {
            size_t src = (size_t)(k0 + j) * N + n;
            tmp[j] = f32 ? f2b(((const float*)W)[src])
                         : ((const unsigned short*)W)[src];
        }
#pragma unroll
        for (int j = 0; j < 8; ++j) wp_all[(size_t)off + (size_t)idx * 8 + j] = tmp[j];
        return;
    }

    if (tid == 0) { s0 = 0; s1 = 0; }
    __syncthreads();
    if (b == 13) {   // edge_index: int64 => all odd 32-bit words zero
        if (tid < 128) {
            if (eidx[2 * tid] != 0) atomicAdd(&s0, 1);
            if (eidx[2 * tid + 1] != 0) atomicAdd(&s1, 1);
        }
        __syncthreads();
        if (tid == 0) flags[2] = (s1 == 0 && s0 > 32) ? 1 : 0;
        return;
    }
    const void* ptrs[13] = {t0, t1, t3, t4, t5, t6, t7, t8, t9, t10, t11, t12, t13};
    const int   cnts[13] = {12800000, 25600000, 8192, 64, 8192, 64,
                            4096, 64, 4096, 2048, 32, 32, 1};
    const int   slot[13] = {0, 1, 3, 4, 5, 6, 7, 8, 9, 10, 11, 12, 13};
    int nsamp = 2 * cnts[b];
    if (nsamp > 1024) nsamp = 1024;
    const unsigned short* h = (const unsigned short*)ptrs[b];
    int susp = 0;
    for (int i = tid; i < nsamp; i += 256)
        if (((h[i] >> 7) & 0xFF) >= 0x90) susp++;
    if (susp) atomicAdd(&s0, susp);
    __syncthreads();
    if (tid == 0) flags[slot[b]] = (s0 * 16 >= nsamp) ? 1 : 0;
}

// ---------------------------------------------------------------------------
// K1 (R19): proj + bucket fused, 2816 blocks interleaved 9:2 per 11.
//   r = b%11: r<9 -> proj sub-block g*9+r; r>=9 -> bucket sub-block g*2+(r-9)
// LDS union: bucket queue 64KB + qcnt 1KB; proj uses first 16KB as bs.
// 65.5KB -> 2 blocks/CU (= proj's measured residency; proj unaffected).
// Both paths are bit-exact R15 code.
// ---------------------------------------------------------------------------
__global__ __launch_bounds__(256) void proj_bucket_kernel(
    const void* __restrict__ evt_x, const void* __restrict__ loc_x,
    const unsigned short* __restrict__ wp_all,
    const void* __restrict__ b_evt, const void* __restrict__ b_loc,
    unsigned short* __restrict__ evt_h, unsigned short* __restrict__ loc_h,
    const int* __restrict__ eidx, uint2* __restrict__ bkt,
    int* __restrict__ gbc, const int* __restrict__ flags) {
    __shared__ uint2 queue[NBKT][QCAP];   // 64 KB (proj: first 16KB = bs)
    __shared__ int qcnt[NBKT];            // 1 KB
    int b = blockIdx.x;
    int g = b / 11, r = b % 11;
    int tid = threadIdx.x;

    if (r >= 9) {
        // ================= bucket path (R15 bit-exact) =================
        int blk = g * 2 + (r - 9);           // 0..511
        qcnt[tid] = 0;
        __syncthreads();
        int f64 = flags[2];
        const long long* e64 = (const long long*)eidx;
        int e0 = blk * PERB;
        int e1 = e0 + PERB; if (e1 > E_CNT) e1 = E_CNT;
        const int rounds = (PERB + 255) / 256;

        for (int rr = 0; rr < rounds; ++rr) {
            int e = e0 + rr * 256 + tid;
            if (e < e1) {
                int src, dst;
                if (f64) { src = (int)e64[e]; dst = (int)e64[E_CNT + e]; }
                else     { src = eidx[e];     dst = eidx[E_CNT + e]; }
                if ((unsigned)dst < (unsigned)N_LOC && (unsigned)src < (unsigned)N_EVT) {
                    int bk = dst / BKT_L;
                    int pos = atomicAdd(&qcnt[bk], 1);
                    if (pos < QCAP) {
                        queue[bk][pos] = make_uint2((unsigned)src, (unsigned)dst);
                    } else {   // overflow (astronomically rare): direct store
                        int p = atomicAdd(&gbc[bk], 1);
                        if (p < CAPG) bkt[(size_t)bk * CAPG + p] = make_uint2(src, dst);
                    }
                }
            }
            __syncthreads();
            // flush phase: thread t owns bucket t
            int n = qcnt[tid]; if (n > QCAP) n = QCAP;
            while (n >= 16) {
                int gp = atomicAdd(&gbc[tid], 16);
                if (gp + 16 <= CAPG) {
                    uint2* d = bkt + (size_t)tid * CAPG + gp;
#pragma unroll
                    for (int j = 0; j < 16; ++j) d[j] = queue[tid][j];
                }
#pragma unroll
                for (int j = 16; j < QCAP; ++j) queue[tid][j - 16] = queue[tid][j];
                n -= 16;
            }
            qcnt[tid] = n;
            __syncthreads();
        }
        // tail flush
        int n = qcnt[tid]; if (n > QCAP) n = QCAP;
        if (n > 0) {
            int gp = atomicAdd(&gbc[tid], n);
            for (int j = 0; j < n; ++j)
                if (gp + j < CAPG) bkt[(size_t)tid * CAPG + gp + j] = queue[tid][j];
        }
        return;
    }

    // ================= proj path (R15 bit-exact) =================
    unsigned short* bs = (unsigned short*)&queue[0][0];   // 16 KB region
    int blk = g * 9 + r;                  // 0..2303
    int lane = tid & 63, wv = tid >> 6;
    int l15 = lane & 15, quad = lane >> 4;

    const void* X; const unsigned short* Wp; const void* bias;
    unsigned short* Y; int fx, fb, w0, nw, ntile;
    if (blk < PROJ_EVT_BLK) {
        X = evt_x; Wp = wp_all;        bias = b_evt; Y = evt_h;
        fx = flags[1]; fb = flags[6];
        w0 = blk * 4 + wv; nw = PROJ_EVT_BLK * 4; ntile = EVT_TILES;
    } else {
        X = loc_x; Wp = wp_all + 8192; bias = b_loc; Y = loc_h;
        fx = flags[0]; fb = flags[4];
        w0 = (blk - PROJ_EVT_BLK) * 4 + wv; nw = PROJ_LOC_BLK * 4; ntile = LOC_TILES;
    }

    // cooperative B stage: 1024 x short8, coalesced
    {
        const short8* src = reinterpret_cast<const short8*>(Wp);
        short8* dst = reinterpret_cast<short8*>(bs);
#pragma unroll
        for (int i = 0; i < 4; ++i) dst[tid + i * 256] = src[tid + i * 256];
    }
    __syncthreads();

    float bv[4];
#pragma unroll
    for (int q = 0; q < 4; ++q) bv[q] = loadf(bias, fb, q * 16 + l15);

    if (w0 >= ntile) return;

    auto mfma_store = [&](const short8* a, int t) {
        floatx4 acc[4];
#pragma unroll
        for (int q = 0; q < 4; ++q) acc[q] = (floatx4)0.0f;
#pragma unroll
        for (int q = 0; q < 4; ++q) {
            short8 bq[4];
#pragma unroll
            for (int kk = 0; kk < 4; ++kk)
                bq[kk] = *reinterpret_cast<const short8*>(
                    &bs[((q * 4 + kk) * 64 + lane) * 8]);
#pragma unroll
            for (int kk = 0; kk < 4; ++kk)
                acc[q] = __builtin_amdgcn_mfma_f32_16x16x32_bf16(
                    a[kk], bq[kk], acc[q], 0, 0, 0);
        }
#pragma unroll
        for (int q = 0; q < 4; ++q)
#pragma unroll
            for (int rr = 0; rr < 4; ++rr) {
                float v = acc[q][rr] + bv[q];
                v = v > 0.0f ? v : 0.0f;
                Y[(size_t)(t * 16 + quad * 4 + rr) * 64 + q * 16 + l15] = f2b(v);
            }
    };

    if (fx) {
        // --- fp32 input path: only pf[8] staging live (32 VGPRs) ---
        const float* Xf = (const float*)X;
        float4 pf[8];
        auto issueF = [&](int t) {
            const float* xr = Xf + (size_t)(t * 16 + l15) * 128 + quad * 8;
#pragma unroll
            for (int kk = 0; kk < 4; ++kk) {
                pf[kk * 2]     = *reinterpret_cast<const float4*>(xr + kk * 32);
                pf[kk * 2 + 1] = *reinterpret_cast<const float4*>(xr + kk * 32 + 4);
            }
        };
        issueF(w0);
        for (int t = w0; t < ntile; t += nw) {
            short8 a[4];
#pragma unroll
            for (int kk = 0; kk < 4; ++kk) {
                float4 p0 = pf[kk * 2], p1 = pf[kk * 2 + 1];
                short8 v;
                v[0] = (short)f2b(p0.x); v[1] = (short)f2b(p0.y);
                v[2] = (short)f2b(p0.z); v[3] = (short)f2b(p0.w);
                v[4] = (short)f2b(p1.x); v[5] = (short)f2b(p1.y);
                v[6] = (short)f2b(p1.z); v[7] = (short)f2b(p1.w);
                a[kk] = v;
            }
            int tn = t + nw;
            if (tn < ntile) issueF(tn);   // next tile in flight during MFMA+store
            mfma_store(a, t);
        }
    } else {
        // --- bf16 input path: only an[4] staging live (16 VGPRs) ---
        const unsigned short* Xh = (const unsigned short*)X;
        short8 an[4];
        auto issueH = [&](int t) {
            const unsigned short* xr = Xh + (size_t)(t * 16 + l15) * 128 + quad * 8;
#pragma unroll
            for (int kk = 0; kk < 4; ++kk)
                an[kk] = *reinterpret_cast<const short8*>(xr + kk * 32);
        };
        issueH(w0);
        for (int t = w0; t < ntile; t += nw) {
            short8 a[4];
#pragma unroll
            for (int kk = 0; kk < 4; ++kk) a[kk] = an[kk];
            int tn = t + nw;
            if (tn < ntile) issueH(tn);
            mfma_store(a, t);
        }
    }
}

// ---------------------------------------------------------------------------
// K2c (R18): per-bucket local CSR build, 512-thread blocks; gbc scan fused.
// ---------------------------------------------------------------------------
__global__ __launch_bounds__(512) void csr_build_kernel(
    const uint2* __restrict__ bkt, const int* __restrict__ gbc,
    int* __restrict__ rowptr, int* __restrict__ csr) {
    __shared__ int sg[256];
    __shared__ int lcnt[512];
    __shared__ int lscan[512];
    __shared__ int lcsr[CAPG];
    int b = blockIdx.x, tid = threadIdx.x;
    int loc0 = b * BKT_L;
    int nloc = N_LOC - loc0; if (nloc > BKT_L) nloc = BKT_L;

    // fused exclusive scan of clamped gbc (first 256 threads; all hit barriers)
    if (tid < 256) {
        int gv = gbc[tid]; if (gv > CAPG) gv = CAPG;
        sg[tid] = gv;
    }
    __syncthreads();
    for (int d = 1; d < 256; d <<= 1) {
        int x = (tid < 256 && tid >= d) ? sg[tid - d] : 0;
        __syncthreads();
        if (tid < 256) sg[tid] += x;
        __syncthreads();
    }
    int cntE = gbc[b]; if (cntE > CAPG) cntE = CAPG;
    int base = sg[b] - cntE;          // exclusive prefix
    const uint2* bp = bkt + (size_t)b * CAPG;

    lcnt[tid] = 0;
    __syncthreads();
    // count (512-thread stride)
    for (int i = tid; i < cntE; i += 512) {
        int d = (int)bp[i].y - loc0;
        atomicAdd(&lcnt[d], 1);
    }
    __syncthreads();
    // inclusive scan over 512 (Hillis-Steele, 1 elem/thread)
    lscan[tid] = lcnt[tid];
    __syncthreads();
    for (int d = 1; d < 512; d <<= 1) {
        int v = (tid >= d) ? lscan[tid - d] : 0;
        __syncthreads();
        lscan[tid] += v;
        __syncthreads();
    }
    // rowptr (exclusive) + reset lcnt to cursor start
    for (int i = tid; i < nloc; i += 512) {
        int excl = lscan[i] - lcnt[i];
        rowptr[loc0 + i] = base + excl;
        lcnt[i] = excl;
    }
    if (b == NBKT - 1 && tid == 0) rowptr[N_LOC] = base + cntE;
    __syncthreads();
    // scatter into LDS csr segment
    for (int i = tid; i < cntE; i += 512) {
        uint2 pr = bp[i];
        int d = (int)pr.y - loc0;
        int p = atomicAdd(&lcnt[d], 1);
        if (p < CAPG) lcsr[p] = (int)pr.x;
    }
    __syncthreads();
    // contiguous flush
    for (int i = tid; i < cntE; i += 512) csr[base + i] = lcsr[i];
}

// ---------------------------------------------------------------------------
// K3: gather-mean, 1 wave per row (100K waves -- parallelism is the point;
// R16's fused 16-row-serial variant measured 73us and regressed). lane =
// (edge eo = lane>>3) x (col-group cg = lane&7, 16B). One VMEM gathers 8
// full 128B rows; 2-deep unroll -> 16 rows in flight per wave.
// ---------------------------------------------------------------------------
__global__ __launch_bounds__(256) void aggregate_kernel(
    const unsigned short* __restrict__ evt_h,
    const int* __restrict__ rowptr, const int* __restrict__ csr,
    unsigned short* __restrict__ agg, int N) {
    int wid  = (blockIdx.x * 256 + threadIdx.x) >> 6;
    int lane = threadIdx.x & 63;
    int eo = lane >> 3, cg = lane & 7;
    if (wid >= N) return;
    int e0 = rowptr[wid], e1 = rowptr[wid + 1];
    float a[8];
#pragma unroll
    for (int k = 0; k < 8; ++k) a[k] = 0.0f;

    int j = e0;
    for (; j + 16 <= e1; j += 16) {
        int s0 = csr[j + eo];
        int s1 = csr[j + 8 + eo];
        ushort8v v0 = *reinterpret_cast<const ushort8v*>(
            evt_h + (size_t)s0 * 64 + cg * 8);
        ushort8v v1 = *reinterpret_cast<const ushort8v*>(
            evt_h + (size_t)s1 * 64 + cg * 8);
#pragma unroll
        for (int k = 0; k < 8; ++k) a[k] += b2f(v0[k]) + b2f(v1[k]);
    }
    for (; j < e1; j += 8) {
        int jj = j + eo;
        bool c = jj < e1;
        int s = csr[c ? jj : j];
        ushort8v v = *reinterpret_cast<const ushort8v*>(
            evt_h + (size_t)s * 64 + cg * 8);
        if (c) {
#pragma unroll
            for (int k = 0; k < 8; ++k) a[k] += b2f(v[k]);
        }
    }
    // reduce across the 8 eo-groups (lanes differing in bits 3..5)
#pragma unroll
    for (int k = 0; k < 8; ++k) {
        a[k] += __shfl_xor(a[k], 8);
        a[k] += __shfl_xor(a[k], 16);
        a[k] += __shfl_xor(a[k], 32);
    }
    float inv = (e1 > e0) ? 1.0f / (float)(e1 - e0) : 0.0f;
    if (eo == 0) {   // lanes 0..7 write 8 x 16B = 128B coalesced
        ushort8v o;
#pragma unroll
        for (int k = 0; k < 8; ++k) o[k] = f2b(a[k] * inv);
        *reinterpret_cast<ushort8v*>(agg + (size_t)wid * 64 + cg * 8) = o;
    }
}

// ---------------------------------------------------------------------------
// K4: SAGE + head via MFMA, persistent waves, three B matrices in LDS
// (20 KB + 8 KB h2s). 1024 blocks, strided. PROVEN (R15).
// ---------------------------------------------------------------------------
__global__ __launch_bounds__(256, 3) void head_kernel(
    const unsigned short* __restrict__ agg,
    const unsigned short* __restrict__ loc_h,
    const unsigned short* __restrict__ wp_all,
    const void* __restrict__ bl, const void* __restrict__ bh1,
    const void* __restrict__ wh2, const void* __restrict__ bh2,
    void* __restrict__ out, const int* __restrict__ flags) {
    __shared__ unsigned short bls[4096];  // W_l frags, 8 KB
    __shared__ unsigned short brs[4096];  // W_r frags, 8 KB
    __shared__ unsigned short b1s[2048];  // W_h1 frags, 4 KB
    __shared__ unsigned short h2s[4][16 * 64];
    int tid = threadIdx.x, lane = tid & 63, wv = tid >> 6;
    int l15 = lane & 15, quad = lane >> 4;
    int fbl = flags[8], fbh1 = flags[11], fwh2 = flags[12], fbh2 = flags[13];
    int fout = flags[0];
    const unsigned short* wp_l  = wp_all + 16384;
    const unsigned short* wp_r  = wp_all + 20480;
    const unsigned short* wp_h1 = wp_all + 24576;

    {   // cooperative stage: coalesced short8 copies
        const short8* sl = reinterpret_cast<const short8*>(wp_l);
        const short8* sr = reinterpret_cast<const short8*>(wp_r);
        const short8* s1 = reinterpret_cast<const short8*>(wp_h1);
        short8* dl = reinterpret_cast<short8*>(bls);
        short8* dr = reinterpret_cast<short8*>(brs);
        short8* d1 = reinterpret_cast<short8*>(b1s);
        dl[tid] = sl[tid]; dl[tid + 256] = sl[tid + 256];
        dr[tid] = sr[tid]; dr[tid + 256] = sr[tid + 256];
        d1[tid] = s1[tid];
    }
    __syncthreads();

    float bbl[4], bh1v[2], w2v[2];
#pragma unroll
    for (int q = 0; q < 4; ++q) bbl[q] = loadf(bl, fbl, q * 16 + l15);
#pragma unroll
    for (int q = 0; q < 2; ++q) {
        bh1v[q] = loadf(bh1, fbh1, q * 16 + l15);
        w2v[q]  = loadf(wh2, fwh2, q * 16 + l15);
    }
    float bb2 = loadf(bh2, fbh2, 0);

    const int NW = HEAD_BLK * 4;   // 4096 waves
    int w0 = blockIdx.x * 4 + wv;
    if (w0 >= NTILES) return;

    short8 c0[4], c1[4];   // [0..1]=agg frags, [2..3]=loc_h frags

    auto issue = [&](short8* c, int t) {
        int m = t * 16 + l15;
#pragma unroll
        for (int kk = 0; kk < 2; ++kk) {
            c[kk]     = *reinterpret_cast<const short8*>(
                agg + (size_t)m * 64 + kk * 32 + quad * 8);
            c[2 + kk] = *reinterpret_cast<const short8*>(
                loc_h + (size_t)m * 64 + kk * 32 + quad * 8);
        }
    };

    auto compute = [&](const short8* c, int tile) {
        floatx4 acc[4];
#pragma unroll
        for (int q = 0; q < 4; ++q) acc[q] = (floatx4)0.0f;
#pragma unroll
        for (int q = 0; q < 4; ++q) {
            short8 bwl[2], bwr[2];
#pragma unroll
            for (int kk = 0; kk < 2; ++kk) {
                bwl[kk] = *reinterpret_cast<const short8*>(
                    &bls[((q * 2 + kk) * 64 + lane) * 8]);
                bwr[kk] = *reinterpret_cast<const short8*>(
                    &brs[((q * 2 + kk) * 64 + lane) * 8]);
            }
#pragma unroll
            for (int kk = 0; kk < 2; ++kk) {
                acc[q] = __builtin_amdgcn_mfma_f32_16x16x32_bf16(
                    c[kk], bwl[kk], acc[q], 0, 0, 0);
                acc[q] = __builtin_amdgcn_mfma_f32_16x16x32_bf16(
                    c[2 + kk], bwr[kk], acc[q], 0, 0, 0);
            }
        }
#pragma unroll
        for (int q = 0; q < 4; ++q)
#pragma unroll
            for (int rr = 0; rr < 4; ++rr) {
                float v = acc[q][rr] + bbl[q];
                v = v > 0.0f ? v : 0.0f;
                h2s[wv][(quad * 4 + rr) * 64 + q * 16 + l15] = f2b(v);
            }
        short8 aH[2];
#pragma unroll
        for (int kk = 0; kk < 2; ++kk)
            aH[kk] = *reinterpret_cast<const short8*>(
                &h2s[wv][l15 * 64 + kk * 32 + quad * 8]);

        floatx4 a1[2];
#pragma unroll
        for (int q = 0; q < 2; ++q) a1[q] = (floatx4)0.0f;
#pragma unroll
        for (int q = 0; q < 2; ++q) {
            short8 bw1[2];
#pragma unroll
            for (int kk = 0; kk < 2; ++kk)
                bw1[kk] = *reinterpret_cast<const short8*>(
                    &b1s[((q * 2 + kk) * 64 + lane) * 8]);
#pragma unroll
            for (int kk = 0; kk < 2; ++kk)
                a1[q] = __builtin_amdgcn_mfma_f32_16x16x32_bf16(
                    aH[kk], bw1[kk], a1[q], 0, 0, 0);
        }

        float s[4] = {0.f, 0.f, 0.f, 0.f};
#pragma unroll
        for (int q = 0; q < 2; ++q)
#pragma unroll
            for (int rr = 0; rr < 4; ++rr) {
                float v = a1[q][rr] + bh1v[q];
                v = v > 0.0f ? v : 0.0f;
                s[rr] += v * w2v[q];
            }
#pragma unroll
        for (int rr = 0; rr < 4; ++rr) {
            s[rr] += __shfl_xor(s[rr], 1);
            s[rr] += __shfl_xor(s[rr], 2);
            s[rr] += __shfl_xor(s[rr], 4);
            s[rr] += __shfl_xor(s[rr], 8);
        }
#pragma unroll
        for (int rr = 0; rr < 4; ++rr) {
            if (l15 == rr) {
                int row = tile * 16 + quad * 4 + rr;
                float v = s[rr] + bb2;
                if (fout) ((float*)out)[row] = v;
                else      ((unsigned short*)out)[row] = f2b(v);
            }
        }
    };

    issue(c0, w0);
    int t = w0;
    while (true) {
        int tn = t + NW;
        bool hn = tn < NTILES;
        if (hn) issue(c1, tn);
        compute(c0, t);
        if (!hn) break;
        t = tn; tn = t + NW; hn = tn < NTILES;
        if (hn) issue(c0, tn);
        compute(c1, t);
        if (!hn) break;
        t = tn;
    }
}

// ---------------------------------------------------------------------------
// Workspace layout (bytes):
//   0:          evt_h    bf16 [200000,64] (25,600,000)
//   25600000:   loc_h    bf16 [100000,64] (12,800,000)
//   38400000:   csr      int [1M]         (4,000,000)
//   42400000:   rowptr   int [100001]     (400,016)
//   42800016:   gbc      int [256]        (1,024)
//   42802064:   wp_all   bf16 [26624]     (53,248)
//   42855312:   flags    int[16]          (64)
//   42855376:   bkt uint2[256][6000] (12,288,000) / agg bf16 (12,800,000)
//               (temporally disjoint: bkt dead after csr_build)
// ---------------------------------------------------------------------------
extern "C" void kernel_launch(void* const* d_in, const int* in_sizes, int n_in,
                              void* d_out, int out_size, void* d_ws, size_t ws_size,
                              hipStream_t stream) {
    (void)in_sizes; (void)n_in; (void)out_size; (void)ws_size;
    const void* loc_x = d_in[0];
    const void* evt_x = d_in[1];
    const int*  eidx  = (const int*)d_in[2];
    const void* W_loc = d_in[3];
    const void* b_loc = d_in[4];
    const void* W_evt = d_in[5];
    const void* b_evt = d_in[6];
    const void* W_l   = d_in[7];
    const void* b_l   = d_in[8];
    const void* W_r   = d_in[9];
    const void* W_h1  = d_in[10];
    const void* b_h1  = d_in[11];
    const void* W_h2  = d_in[12];
    const void* b_h2  = d_in[13];

    char* ws = (char*)d_ws;
    unsigned short* evt_h  = (unsigned short*)(ws);
    unsigned short* loc_h  = (unsigned short*)(ws + 25600000);
    int*            csr    = (int*)(ws + 38400000);
    int*            rowptr = (int*)(ws + 42400000);
    int*            gbc    = (int*)(ws + 42800016);
    unsigned short* wp_all = (unsigned short*)(ws + 42802064);
    int*            flags  = (int*)(ws + 42855312);
    uint2*          bkt    = (uint2*)(ws + 42855376);
    unsigned short* agg    = (unsigned short*)(ws + 42855376);

    prep_kernel<<<28, 256, 0, stream>>>(
        loc_x, evt_x, eidx, W_loc, b_loc, W_evt, b_evt,
        W_l, b_l, W_r, W_h1, b_h1, W_h2, b_h2,
        flags, gbc, wp_all);

    proj_bucket_kernel<<<PB_TOT, 256, 0, stream>>>(
        evt_x, loc_x, wp_all, b_evt, b_loc, evt_h, loc_h,
        eidx, bkt, gbc, flags);

    csr_build_kernel<<<NBKT, 512, 0, stream>>>(bkt, gbc, rowptr, csr);

    aggregate_kernel<<<(N_LOC + 3) / 4, 256, 0, stream>>>(evt_h, rowptr, csr,
                                                          agg, N_LOC);

    head_kernel<<<HEAD_BLK, 256, 0, stream>>>(
        agg, loc_h, wp_all, b_l, b_h1, W_h2, b_h2, d_out, flags);
}